// Round 5
// baseline (177.914 us; speedup 1.0000x reference)
//
#include <hip/hip_runtime.h>
#include <stdint.h>

#define NH 16
#define DKH 64
#define SEQ 2048
#define NBATCH 2
#define NROW (NBATCH*SEQ)   // 4096
#define DM 1024
#define LOG2E 1.44269504088896f

typedef __attribute__((ext_vector_type(8))) __bf16 bf16x8;
typedef __attribute__((ext_vector_type(4))) __bf16 bf16x4;
typedef __attribute__((ext_vector_type(4))) float f32x4;
typedef __attribute__((ext_vector_type(16))) float f32x16;

__device__ __forceinline__ unsigned short f2bf(float f) {
  union { float f; uint32_t u; } v; v.f = f;
  uint32_t r = v.u + 0x7FFFu + ((v.u >> 16) & 1u);
  return (unsigned short)(r >> 16);
}
__device__ __forceinline__ float bf2f(unsigned short b) {
  union { uint32_t u; float f; } v; v.u = ((uint32_t)b) << 16;
  return v.f;
}
__device__ __forceinline__ f32x4 mfma16(bf16x8 a, bf16x8 b, f32x4 c) {
  return __builtin_amdgcn_mfma_f32_16x16x32_bf16(a, b, c, 0, 0, 0);
}
__device__ __forceinline__ f32x16 mfma32(bf16x8 a, bf16x8 b, f32x16 c) {
  return __builtin_amdgcn_mfma_f32_32x32x16_bf16(a, b, c, 0, 0, 0);
}
// async global->LDS, 16B/lane; LDS dest = wave-uniform base + lane*16
__device__ __forceinline__ void gload_lds16(const void* g, void* l) {
  __builtin_amdgcn_global_load_lds(
      (__attribute__((address_space(1))) uint32_t*)(uintptr_t)g,
      (__attribute__((address_space(3))) uint32_t*)(uintptr_t)l,
      16, 0, 0);
}

// ---------------- k0: x f32 -> bf16 ----------------
__global__ __launch_bounds__(256) void k_cvt_x(const float* __restrict__ x,
                                               unsigned short* __restrict__ xb) {
  int i = blockIdx.x * 256 + threadIdx.x;
  float4 v = ((const float4*)x)[i];
  ushort4 o;
  o.x = f2bf(v.x); o.y = f2bf(v.y); o.z = f2bf(v.z); o.w = f2bf(v.w);
  ((ushort4*)xb)[i] = o;
}

// ---------------- k1: W[k][n] f32 -> Wt[n][k] bf16 (Wo: hi+lo split) -------
__global__ __launch_bounds__(256) void k_cvt_w(
    const float* __restrict__ Wq, const float* __restrict__ Wk,
    const float* __restrict__ Wv, const float* __restrict__ Wo,
    unsigned short* __restrict__ Wqt, unsigned short* __restrict__ Wkt,
    unsigned short* __restrict__ Wvt,
    unsigned short* __restrict__ Woth, unsigned short* __restrict__ Wotl) {
  __shared__ float tile[32][33];
  int z = blockIdx.z;
  const float* W = (z == 0) ? Wq : (z == 1) ? Wk : (z == 2) ? Wv : Wo;
  int ti = blockIdx.x, tj = blockIdx.y;      // k-tile, n-tile
  int c = threadIdx.x & 31, r0 = threadIdx.x >> 5;
#pragma unroll
  for (int rr = 0; rr < 4; ++rr) {
    int r = r0 + rr * 8;
    tile[r][c] = W[(ti * 32 + r) * DM + tj * 32 + c];
  }
  __syncthreads();
#pragma unroll
  for (int rr = 0; rr < 4; ++rr) {
    int a = r0 + rr * 8;                     // n within tile
    float v = tile[c][a];                    // = W[ti*32+c][tj*32+a]
    int idx = (tj * 32 + a) * DM + ti * 32 + c;
    if (z == 0) Wqt[idx] = f2bf(v);
    else if (z == 1) Wkt[idx] = f2bf(v);
    else if (z == 2) Wvt[idx] = f2bf(v);
    else {
      unsigned short h = f2bf(v);
      Woth[idx] = h;
      Wotl[idx] = f2bf(v - bf2f(h));
    }
  }
}

// ---------------- k2: QKV projection GEMM (bf16 MFMA, 128x128x64) ---------
__global__ __launch_bounds__(256) void k_gemm_qkv(
    const unsigned short* __restrict__ xb,
    const unsigned short* __restrict__ Wqt, const unsigned short* __restrict__ Wkt,
    const unsigned short* __restrict__ Wvt,
    const float* __restrict__ bq, const float* __restrict__ bk,
    const float* __restrict__ bv,
    unsigned short* __restrict__ Q, unsigned short* __restrict__ Ko,
    unsigned short* __restrict__ Vt) {
  __shared__ __align__(16) unsigned short Al[128 * 64];
  __shared__ __align__(16) unsigned short Bl[128 * 64];
  int z = blockIdx.z;
  const unsigned short* Wt = (z == 0) ? Wqt : (z == 1) ? Wkt : Wvt;
  const float* bias = (z == 0) ? bq : (z == 1) ? bk : bv;

  int m0 = blockIdx.x * 128, n0 = blockIdx.y * 128;
  int tid = threadIdx.x, lane = tid & 63, wave = tid >> 6;
  int wr = wave >> 1, wc = wave & 1;
  int l15 = lane & 15, lg = lane >> 4;
  int r3 = lane >> 3, s3 = lane & 7;
  int gsw = (s3 ^ r3) << 4;      // pre-swizzled source slot (bytes), row&7 == r3
  int swz = l15 & 7;             // read-side row XOR

  f32x4 acc[4][4] = {};

  for (int kb = 0; kb < 16; ++kb) {
#pragma unroll
    for (int c = 0; c < 4; ++c) {
      int rb = c * 32 + wave * 8;            // wave-uniform row base (mult of 8)
      gload_lds16((const char*)xb + (size_t)(m0 + rb + r3) * 2048 + kb * 128 + gsw,
                  (char*)Al + rb * 128);
      gload_lds16((const char*)Wt + (size_t)(n0 + rb + r3) * 2048 + kb * 128 + gsw,
                  (char*)Bl + rb * 128);
    }
    __syncthreads();
#pragma unroll
    for (int ks = 0; ks < 2; ++ks) {
      int slot = lg + 4 * ks;
      int sofs = ((slot ^ swz) << 4);
      bf16x8 a[4], b[4];
#pragma unroll
      for (int mt = 0; mt < 4; ++mt)
        a[mt] = *(const bf16x8*)((const char*)Al + (wr * 64 + mt * 16 + l15) * 128 + sofs);
#pragma unroll
      for (int nt = 0; nt < 4; ++nt)
        b[nt] = *(const bf16x8*)((const char*)Bl + (wc * 64 + nt * 16 + l15) * 128 + sofs);
#pragma unroll
      for (int mt = 0; mt < 4; ++mt)
#pragma unroll
        for (int nt = 0; nt < 4; ++nt)
          acc[mt][nt] = mfma16(a[mt], b[nt], acc[mt][nt]);
    }
    __syncthreads();
  }

#pragma unroll
  for (int nt = 0; nt < 4; ++nt) {
    int n = n0 + wc * 64 + nt * 16 + l15;
    float bb = bias[n];
    int h = n >> 6, dk = n & 63;
#pragma unroll
    for (int mt = 0; mt < 4; ++mt) {
      int mbase = m0 + wr * 64 + mt * 16 + lg * 4;
      int bidx = mbase >> 11, s = mbase & 2047;
      if (z < 2) {
        unsigned short* Out = (z == 0) ? Q : Ko;
#pragma unroll
        for (int r = 0; r < 4; ++r)
          Out[(((size_t)(bidx * NH + h)) * SEQ + s + r) * DKH + dk] =
              f2bf(acc[mt][nt][r] + bb);
      } else {
        ushort4 pk;
        pk.x = f2bf(acc[mt][nt][0] + bb);
        pk.y = f2bf(acc[mt][nt][1] + bb);
        pk.z = f2bf(acc[mt][nt][2] + bb);
        pk.w = f2bf(acc[mt][nt][3] + bb);
        *(ushort4*)&Vt[((size_t)(bidx * NH + h) * DKH + dk) * SEQ + s] = pk;
      }
    }
  }
}

// ---------------- k3: chunk-causal flash attention (v3) -------------------
// Barrier-free main loop. 4 waves: w = (qh<<1)|kh; wave tile = 32q x 32k via
// mfma_32x32x16 (swapped QK^T). Each wave stages ITS OWN K/V fragments
// (frag-linear LDS, contiguous reads), double-buffered, counted vmcnt(8).
// Fixed-max softmax (M=6 in bias table), per-lane lsum, P via 4x ds_write_b64.
// Cross-wave (kh) reduction once at end through LDS scratch.
__global__ __launch_bounds__(256) void k_attn(
    const unsigned short* __restrict__ Qg, const unsigned short* __restrict__ Kg,
    const unsigned short* __restrict__ Vtg, const float* __restrict__ rel_bias,
    unsigned short* __restrict__ AOh, unsigned short* __restrict__ AOl) {
  __shared__ __align__(16) char ldsK[2][4][4096];   // [buf][wave][dkt*1024 + lane*16]
  __shared__ __align__(16) char ldsV[2][4][4096];   // [buf][wave][(nt*2+kt)*1024 + lane*16]
  __shared__ __align__(16) unsigned short Pl[4][32 * 40];
  __shared__ float biasl[257];

  int blk = blockIdx.x;
  int bh = blk & 31;                 // XCD-affine
  int qc = 31 - (blk >> 5);          // longest first
  int h = bh & 15, bidx = bh >> 4;
  int tid = threadIdx.x, lane = tid & 63, w = tid >> 6;
  int l31 = lane & 31, hi = lane >> 5;
  int qh = w >> 1, kh = w & 1;

  const float C1L = 0.125f * LOG2E;
  for (int i = tid; i < 257; i += 256)
    biasl[i] = rel_bias[i * NH + h] * LOG2E - 6.0f * LOG2E;
  float cfar = rel_bias[256 * NH + h] * LOG2E - 6.0f * LOG2E;
  __syncthreads();   // biasl visible; only block-wide sync until epilogue

  // Q fragments (B-operand): lane l31 = q-row, hi = dk-halfgroup
  int qrow = qc * 64 + qh * 32 + l31;
  const unsigned short* qp = Qg + ((size_t)bh * SEQ + qrow) * DKH + hi * 8;
  bf16x8 qf[4];
#pragma unroll
  for (int d = 0; d < 4; ++d) qf[d] = *(const bf16x8*)(qp + d * 16);

  const char* kcb = (const char*)(Kg + (size_t)bh * SEQ * DKH);
  const char* vcb = (const char*)(Vtg + (size_t)bh * DKH * SEQ);
  // per-lane frag sources
  const char* kSrc = kcb + (kh * 32 + l31) * 128 + hi * 16;
  const char* vSrc = vcb + (size_t)l31 * (SEQ * 2) + kh * 64 + hi * 16;

  unsigned short* PlW = &Pl[w][0];

  auto stage = [&](int j, char* kb, char* vb) {
#pragma unroll
    for (int d = 0; d < 4; ++d)
      gload_lds16(kSrc + (size_t)j * 8192 + d * 32, kb + d * 1024);
#pragma unroll
    for (int nt = 0; nt < 2; ++nt)
#pragma unroll
      for (int kt = 0; kt < 2; ++kt)
        gload_lds16(vSrc + (size_t)nt * 32 * (SEQ * 2) + (size_t)j * 128 + kt * 32,
                    vb + (nt * 2 + kt) * 1024);
  };

  float lsum = 0.f;
  f32x16 acc0 = {}, acc1 = {};

  stage(0, &ldsK[0][w][0], &ldsV[0][w][0]);
  if (qc > 0) stage(1, &ldsK[1][w][0], &ldsV[1][w][0]);

  for (int j = 0; j <= qc; ++j) {
    char* Kb = (j & 1) ? &ldsK[1][w][0] : &ldsK[0][w][0];
    char* Vb = (j & 1) ? &ldsV[1][w][0] : &ldsV[0][w][0];
    if (j < qc) asm volatile("s_waitcnt vmcnt(8)" ::: "memory");
    else        asm volatile("s_waitcnt vmcnt(0)" ::: "memory");

    // QK^T (swapped): sa reg r -> key = j*64 + kh*32 + (r&3)+8*(r>>2)+4*hi, q = qrow
    f32x16 sa = {};
    __builtin_amdgcn_s_setprio(1);
#pragma unroll
    for (int d = 0; d < 4; ++d) {
      bf16x8 kf = *(const bf16x8*)(Kb + d * 1024 + lane * 16);
      sa = mfma32(kf, qf[d], sa);
    }
    __builtin_amdgcn_s_setprio(0);

    float pr[16];
    if (j >= qc - 2) {
      int kb0 = j * 64 + kh * 32 + 4 * hi;
#pragma unroll
      for (int r = 0; r < 16; ++r) {
        int k = kb0 + (r & 3) + 8 * (r >> 2);
        int rel = qrow - k;
        rel = min(max(rel, -128), 128) + 128;
        pr[r] = exp2f(fmaf(sa[r], C1L, biasl[rel]));
      }
    } else {
#pragma unroll
      for (int r = 0; r < 16; ++r)
        pr[r] = exp2f(fmaf(sa[r], C1L, cfar));
    }
    lsum += (((pr[0] + pr[1]) + (pr[2] + pr[3])) + ((pr[4] + pr[5]) + (pr[6] + pr[7]))) +
            (((pr[8] + pr[9]) + (pr[10] + pr[11])) + ((pr[12] + pr[13]) + (pr[14] + pr[15])));

    // P -> LDS: run g = keys-local {8g+4hi .. +3}, one b64 per run
#pragma unroll
    for (int g = 0; g < 4; ++g) {
      bf16x4 pk;
      pk[0] = (__bf16)pr[g * 4 + 0]; pk[1] = (__bf16)pr[g * 4 + 1];
      pk[2] = (__bf16)pr[g * 4 + 2]; pk[3] = (__bf16)pr[g * 4 + 3];
      *(bf16x4*)(PlW + l31 * 40 + g * 8 + hi * 4) = pk;
    }

    // PV: A = P rows (lane=q), B = V frags (lane=dv)
    bf16x8 pa0 = *(const bf16x8*)(PlW + l31 * 40 + hi * 8);
    bf16x8 pa1 = *(const bf16x8*)(PlW + l31 * 40 + 16 + hi * 8);
    bf16x8 v00 = *(const bf16x8*)(Vb + 0 * 1024 + lane * 16);
    bf16x8 v01 = *(const bf16x8*)(Vb + 1 * 1024 + lane * 16);
    bf16x8 v10 = *(const bf16x8*)(Vb + 2 * 1024 + lane * 16);
    bf16x8 v11 = *(const bf16x8*)(Vb + 3 * 1024 + lane * 16);
    __builtin_amdgcn_s_setprio(1);
    acc0 = mfma32(pa0, v00, acc0);
    acc0 = mfma32(pa1, v01, acc0);
    acc1 = mfma32(pa0, v10, acc1);
    acc1 = mfma32(pa1, v11, acc1);
    __builtin_amdgcn_s_setprio(0);

    asm volatile("s_waitcnt lgkmcnt(0)" ::: "memory");
    if (j + 2 <= qc) stage(j + 2, Kb, Vb);   // refill the buffer just consumed
  }

  // ---- cross-wave (kh) reduction + epilogue ----
  lsum += __shfl_xor(lsum, 32);
  __syncthreads();
  float* scr  = (float*)&ldsK[0][0][0];              // 16 KB
  float* scrL = (float*)&ldsV[0][0][0];              // 64 floats
  if (kh == 1) {
#pragma unroll
    for (int r = 0; r < 16; ++r) {
      scr[(qh * 32 + r) * 64 + lane]      = acc0[r];
      scr[(qh * 32 + 16 + r) * 64 + lane] = acc1[r];
    }
    if (hi == 0) scrL[qh * 32 + l31] = lsum;
  }
  __syncthreads();
  if (kh == 0) {
    lsum += scrL[qh * 32 + l31];
#pragma unroll
    for (int r = 0; r < 16; ++r) {
      acc0[r] += scr[(qh * 32 + r) * 64 + lane];
      acc1[r] += scr[(qh * 32 + 16 + r) * 64 + lane];
    }
#pragma unroll
    for (int r = 0; r < 16; ++r) {
      int ql = (r & 3) + 8 * (r >> 2) + 4 * hi;
      float inv = 1.0f / __shfl(lsum, ql, 64);
      size_t row = (size_t)bidx * SEQ + qc * 64 + qh * 32 + ql;
      {
        float v = acc0[r] * inv; unsigned short hh = f2bf(v);
        int col = h * 64 + l31;
        AOh[row * DM + col] = hh; AOl[row * DM + col] = f2bf(v - bf2f(hh));
      }
      {
        float v = acc1[r] * inv; unsigned short hh = f2bf(v);
        int col = h * 64 + 32 + l31;
        AOh[row * DM + col] = hh; AOl[row * DM + col] = f2bf(v - bf2f(hh));
      }
    }
  }
}

// ---------------- k4: output GEMM, split-bf16 (3 MFMAs), f32 out ----------
__global__ __launch_bounds__(256) void k_gemm_out(
    const unsigned short* __restrict__ Ah, const unsigned short* __restrict__ Alo,
    const unsigned short* __restrict__ Bh, const unsigned short* __restrict__ Blo,
    const float* __restrict__ bo, float* __restrict__ out) {
  __shared__ __align__(16) unsigned short sAh[128 * 32];
  __shared__ __align__(16) unsigned short sAl[128 * 32];
  __shared__ __align__(16) unsigned short sBh[128 * 32];
  __shared__ __align__(16) unsigned short sBl[128 * 32];
  int m0 = blockIdx.x * 128, n0 = blockIdx.y * 128;
  int tid = threadIdx.x, lane = tid & 63, wave = tid >> 6;
  int wr = wave >> 1, wc = wave & 1;
  int l15 = lane & 15, lg = lane >> 4;
  int rq = lane >> 2;                                  // 0..15, row offset
  int gsw2 = (((lane & 3) ^ ((lane >> 3) & 3)) << 4);  // source slot (bytes)
  int pswz = (l15 >> 1) & 3;                           // read-side row XOR

  f32x4 acc[4][4] = {};

  for (int kb = 0; kb < 32; ++kb) {
#pragma unroll
    for (int c = 0; c < 2; ++c) {
      int rb = c * 64 + wave * 16;           // wave-uniform row base (mult of 16)
      size_t ga = (size_t)(m0 + rb + rq) * 2048 + (size_t)kb * 64 + gsw2;
      size_t gb = (size_t)(n0 + rb + rq) * 2048 + (size_t)kb * 64 + gsw2;
      size_t lofs = (size_t)rb * 64;
      gload_lds16((const char*)Ah + ga, (char*)sAh + lofs);
      gload_lds16((const char*)Alo + ga, (char*)sAl + lofs);
      gload_lds16((const char*)Bh + gb, (char*)sBh + lofs);
      gload_lds16((const char*)Blo + gb, (char*)sBl + lofs);
    }
    __syncthreads();
    int sofs = ((lg ^ pswz) << 4);
    bf16x8 ah[4], al[4], bh[4], bl[4];
#pragma unroll
    for (int mt = 0; mt < 4; ++mt) {
      size_t rp = (size_t)((wr * 64 + mt * 16 + l15) * 64 + sofs);
      ah[mt] = *(const bf16x8*)((const char*)sAh + rp);
      al[mt] = *(const bf16x8*)((const char*)sAl + rp);
    }
#pragma unroll
    for (int nt = 0; nt < 4; ++nt) {
      size_t rp = (size_t)((wc * 64 + nt * 16 + l15) * 64 + sofs);
      bh[nt] = *(const bf16x8*)((const char*)sBh + rp);
      bl[nt] = *(const bf16x8*)((const char*)sBl + rp);
    }
#pragma unroll
    for (int mt = 0; mt < 4; ++mt)
#pragma unroll
      for (int nt = 0; nt < 4; ++nt) {
        acc[mt][nt] = mfma16(ah[mt], bh[nt], acc[mt][nt]);
        acc[mt][nt] = mfma16(al[mt], bh[nt], acc[mt][nt]);
        acc[mt][nt] = mfma16(ah[mt], bl[nt], acc[mt][nt]);
      }
    __syncthreads();
  }

#pragma unroll
  for (int nt = 0; nt < 4; ++nt) {
    int n = n0 + wc * 64 + nt * 16 + l15;
    float bb = bo[n];
#pragma unroll
    for (int mt = 0; mt < 4; ++mt) {
      int mbase = m0 + wr * 64 + mt * 16 + lg * 4;
#pragma unroll
      for (int r = 0; r < 4; ++r)
        out[(size_t)(mbase + r) * DM + n] = acc[mt][nt][r] + bb;
    }
  }
}

// ---------------- launch ---------------------------------------------------
extern "C" void kernel_launch(void* const* d_in, const int* in_sizes, int n_in,
                              void* d_out, int out_size, void* d_ws, size_t ws_size,
                              hipStream_t stream) {
  const float* x  = (const float*)d_in[0];
  const float* Wq = (const float*)d_in[1];
  const float* bq = (const float*)d_in[2];
  const float* Wk = (const float*)d_in[3];
  const float* bk = (const float*)d_in[4];
  const float* Wv = (const float*)d_in[5];
  const float* bv = (const float*)d_in[6];
  const float* Wo = (const float*)d_in[7];
  const float* bo = (const float*)d_in[8];
  const float* rb = (const float*)d_in[9];
  float* out = (float*)d_out;

  char* ws = (char*)d_ws;
  size_t off = 0;
  auto alloc = [&](size_t bytes) {
    char* p = ws + off; off += (bytes + 255) & ~(size_t)255; return p;
  };
  unsigned short* xb   = (unsigned short*)alloc((size_t)NROW * DM * 2);
  unsigned short* Wqt  = (unsigned short*)alloc((size_t)DM * DM * 2);
  unsigned short* Wkt  = (unsigned short*)alloc((size_t)DM * DM * 2);
  unsigned short* Wvt  = (unsigned short*)alloc((size_t)DM * DM * 2);
  unsigned short* Woth = (unsigned short*)alloc((size_t)DM * DM * 2);
  unsigned short* Wotl = (unsigned short*)alloc((size_t)DM * DM * 2);
  unsigned short* Qb   = (unsigned short*)alloc((size_t)NROW * DM * 2);
  unsigned short* Kb   = (unsigned short*)alloc((size_t)NROW * DM * 2);
  unsigned short* Vtb  = (unsigned short*)alloc((size_t)NROW * DM * 2);
  unsigned short* AOh  = (unsigned short*)alloc((size_t)NROW * DM * 2);
  unsigned short* AOl  = (unsigned short*)alloc((size_t)NROW * DM * 2);

  k_cvt_x<<<dim3(NROW * DM / 4 / 256), dim3(256), 0, stream>>>(x, xb);
  k_cvt_w<<<dim3(32, 32, 4), dim3(256), 0, stream>>>(Wq, Wk, Wv, Wo,
                                                     Wqt, Wkt, Wvt, Woth, Wotl);
  k_gemm_qkv<<<dim3(32, 8, 3), dim3(256), 0, stream>>>(xb, Wqt, Wkt, Wvt,
                                                       bq, bk, bv, Qb, Kb, Vtb);
  k_attn<<<dim3(1024), dim3(256), 0, stream>>>(Qb, Kb, Vtb, rb, AOh, AOl);
  k_gemm_out<<<dim3(32, 8), dim3(256), 0, stream>>>(AOh, AOl, Woth, Wotl, bo, out);
}

// Round 6
// 123.428 us; speedup vs baseline: 1.4414x; 1.4414x over previous
//
#include <hip/hip_runtime.h>
#include <stdint.h>

#define NH 16
#define DKH 64
#define SEQ 2048
#define NBATCH 2
#define NROW (NBATCH*SEQ)   // 4096
#define DM 1024
#define LOG2E 1.44269504088896f

typedef __attribute__((ext_vector_type(8))) __bf16 bf16x8;
typedef __attribute__((ext_vector_type(4))) float f32x4;

__device__ __forceinline__ unsigned short f2bf(float f) {
  union { float f; uint32_t u; } v; v.f = f;
  uint32_t r = v.u + 0x7FFFu + ((v.u >> 16) & 1u);
  return (unsigned short)(r >> 16);
}
__device__ __forceinline__ float bf2f(unsigned short b) {
  union { uint32_t u; float f; } v; v.u = ((uint32_t)b) << 16;
  return v.f;
}
__device__ __forceinline__ f32x4 mfma16(bf16x8 a, bf16x8 b, f32x4 c) {
  return __builtin_amdgcn_mfma_f32_16x16x32_bf16(a, b, c, 0, 0, 0);
}
// async global->LDS, 16B/lane; LDS dest = wave-uniform base + lane*16
__device__ __forceinline__ void gload_lds16(const void* g, void* l) {
  __builtin_amdgcn_global_load_lds(
      (__attribute__((address_space(1))) uint32_t*)(uintptr_t)g,
      (__attribute__((address_space(3))) uint32_t*)(uintptr_t)l,
      16, 0, 0);
}

// ---------------- k0: x f32 -> bf16 ----------------
__global__ __launch_bounds__(256) void k_cvt_x(const float* __restrict__ x,
                                               unsigned short* __restrict__ xb) {
  int i = blockIdx.x * 256 + threadIdx.x;
  float4 v = ((const float4*)x)[i];
  ushort4 o;
  o.x = f2bf(v.x); o.y = f2bf(v.y); o.z = f2bf(v.z); o.w = f2bf(v.w);
  ((ushort4*)xb)[i] = o;
}

// ---------------- k1: W[k][n] f32 -> Wt[n][k] bf16 ------------------------
__global__ __launch_bounds__(256) void k_cvt_w(
    const float* __restrict__ Wq, const float* __restrict__ Wk,
    const float* __restrict__ Wv, const float* __restrict__ Wo,
    unsigned short* __restrict__ Wqt, unsigned short* __restrict__ Wkt,
    unsigned short* __restrict__ Wvt, unsigned short* __restrict__ Wot) {
  __shared__ float tile[32][33];
  int z = blockIdx.z;
  const float* W = (z == 0) ? Wq : (z == 1) ? Wk : (z == 2) ? Wv : Wo;
  int ti = blockIdx.x, tj = blockIdx.y;      // k-tile, n-tile
  int c = threadIdx.x & 31, r0 = threadIdx.x >> 5;
#pragma unroll
  for (int rr = 0; rr < 4; ++rr) {
    int r = r0 + rr * 8;
    tile[r][c] = W[(ti * 32 + r) * DM + tj * 32 + c];
  }
  __syncthreads();
  unsigned short* Out = (z == 0) ? Wqt : (z == 1) ? Wkt : (z == 2) ? Wvt : Wot;
#pragma unroll
  for (int rr = 0; rr < 4; ++rr) {
    int a = r0 + rr * 8;                     // n within tile
    float v = tile[c][a];                    // = W[ti*32+c][tj*32+a]
    Out[(tj * 32 + a) * DM + ti * 32 + c] = f2bf(v);
  }
}

// ---------------- k2: QKV projection GEMM (bf16 MFMA, 128x128x64) ---------
// LDS tiles linear [128][64] shorts (128B rows, 8 x 16B slots/row).
// Swizzle: logical slot s of row r stored at position s ^ (r&7).
__global__ __launch_bounds__(256) void k_gemm_qkv(
    const unsigned short* __restrict__ xb,
    const unsigned short* __restrict__ Wqt, const unsigned short* __restrict__ Wkt,
    const unsigned short* __restrict__ Wvt,
    const float* __restrict__ bq, const float* __restrict__ bk,
    const float* __restrict__ bv,
    unsigned short* __restrict__ Q, unsigned short* __restrict__ Ko,
    unsigned short* __restrict__ Vt) {
  __shared__ __align__(16) unsigned short Al[128 * 64];
  __shared__ __align__(16) unsigned short Bl[128 * 64];
  int z = blockIdx.z;
  const unsigned short* Wt = (z == 0) ? Wqt : (z == 1) ? Wkt : Wvt;
  const float* bias = (z == 0) ? bq : (z == 1) ? bk : bv;

  int m0 = blockIdx.x * 128, n0 = blockIdx.y * 128;
  int tid = threadIdx.x, lane = tid & 63, wave = tid >> 6;
  int wr = wave >> 1, wc = wave & 1;
  int l15 = lane & 15, lg = lane >> 4;
  int r3 = lane >> 3, s3 = lane & 7;
  int gsw = (s3 ^ r3) << 4;      // pre-swizzled source slot (bytes), row&7 == r3
  int swz = l15 & 7;             // read-side row XOR

  f32x4 acc[4][4] = {};

  for (int kb = 0; kb < 16; ++kb) {
#pragma unroll
    for (int c = 0; c < 4; ++c) {
      int rb = c * 32 + wave * 8;            // wave-uniform row base (mult of 8)
      gload_lds16((const char*)xb + (size_t)(m0 + rb + r3) * 2048 + kb * 128 + gsw,
                  (char*)Al + rb * 128);
      gload_lds16((const char*)Wt + (size_t)(n0 + rb + r3) * 2048 + kb * 128 + gsw,
                  (char*)Bl + rb * 128);
    }
    __syncthreads();
#pragma unroll
    for (int ks = 0; ks < 2; ++ks) {
      int slot = lg + 4 * ks;
      int sofs = ((slot ^ swz) << 4);
      bf16x8 a[4], b[4];
#pragma unroll
      for (int mt = 0; mt < 4; ++mt)
        a[mt] = *(const bf16x8*)((const char*)Al + (wr * 64 + mt * 16 + l15) * 128 + sofs);
#pragma unroll
      for (int nt = 0; nt < 4; ++nt)
        b[nt] = *(const bf16x8*)((const char*)Bl + (wc * 64 + nt * 16 + l15) * 128 + sofs);
#pragma unroll
      for (int mt = 0; mt < 4; ++mt)
#pragma unroll
        for (int nt = 0; nt < 4; ++nt)
          acc[mt][nt] = mfma16(a[mt], b[nt], acc[mt][nt]);
    }
    __syncthreads();
  }

#pragma unroll
  for (int nt = 0; nt < 4; ++nt) {
    int n = n0 + wc * 64 + nt * 16 + l15;
    float bb = bias[n];
    int h = n >> 6, dk = n & 63;
#pragma unroll
    for (int mt = 0; mt < 4; ++mt) {
      int mbase = m0 + wr * 64 + mt * 16 + lg * 4;
      int bidx = mbase >> 11, s = mbase & 2047;
      if (z < 2) {
        unsigned short* Out = (z == 0) ? Q : Ko;
#pragma unroll
        for (int r = 0; r < 4; ++r)
          Out[(((size_t)(bidx * NH + h)) * SEQ + s + r) * DKH + dk] =
              f2bf(acc[mt][nt][r] + bb);
      } else {
        ushort4 pk;
        pk.x = f2bf(acc[mt][nt][0] + bb);
        pk.y = f2bf(acc[mt][nt][1] + bb);
        pk.z = f2bf(acc[mt][nt][2] + bb);
        pk.w = f2bf(acc[mt][nt][3] + bb);
        *(ushort4*)&Vt[((size_t)(bidx * NH + h) * DKH + dk) * SEQ + s] = pk;
      }
    }
  }
}

// ---------------- k3: chunk-causal flash attention (v2, round-4) ----------
// grid 1024: bh = blk&31 (XCD affinity), qc = 31-(blk>>5) (longest first).
// Fixed-max softmax (M=6 folded into bias table), deferred row-sum.
// K/V staged via global_load_lds with XOR-swizzled source, double-buffered.
__global__ __launch_bounds__(256) void k_attn(
    const unsigned short* __restrict__ Qg, const unsigned short* __restrict__ Kg,
    const unsigned short* __restrict__ Vtg, const float* __restrict__ rel_bias,
    unsigned short* __restrict__ AOh) {
  __shared__ __align__(16) unsigned short Kl[2][64 * 64];
  __shared__ __align__(16) unsigned short Vl[2][64 * 64];
  __shared__ __align__(16) unsigned short Pl[64 * 72];
  __shared__ float biasl[257];

  int blk = blockIdx.x;
  int bh = blk & 31;
  int qc = 31 - (blk >> 5);
  int h = bh & 15, bidx = bh >> 4;
  int tid = threadIdx.x, lane = tid & 63, wave = tid >> 6;
  int l15 = lane & 15, lg = lane >> 4;
  int r3 = lane >> 3, s3 = lane & 7;
  int gsw = (s3 ^ r3) * 16;   // pre-swizzled source slot (bytes)

  const float C1L = 0.125f * LOG2E;

  // bias table pre-scaled: (rel_bias - 6) * log2(e)
  for (int i = tid; i < 257; i += 256)
    biasl[i] = rel_bias[i * NH + h] * LOG2E - 6.0f * LOG2E;

  // Q fragments in registers for the whole block
  int qrow = qc * 64 + wave * 16 + l15;
  const unsigned short* qptr = Qg + ((size_t)bh * SEQ + qrow) * DKH + lg * 8;
  bf16x8 qf0 = *(const bf16x8*)(qptr);
  bf16x8 qf1 = *(const bf16x8*)(qptr + 32);

  const char* kcb = (const char*)(Kg + (size_t)bh * SEQ * DKH);
  const char* vcb = (const char*)(Vtg + (size_t)bh * DKH * SEQ);

  // stage K/V chunk j into buffer b: LDS[row][slot16] = G[row][slot16 ^ (row&7)]
  auto stage = [&](int j, int b) {
    const char* kj = kcb + (size_t)j * (64 * DKH * 2);
    const char* vj = vcb + (size_t)j * 128;
#pragma unroll
    for (int c = 0; c < 2; ++c) {
      int rb = wave * 16 + c * 8;          // wave-uniform row base
      gload_lds16(kj + (size_t)(rb + r3) * 128 + gsw,
                  (char*)&Kl[b][0] + rb * 128);
      gload_lds16(vj + (size_t)(rb + r3) * (SEQ * 2) + gsw,
                  (char*)&Vl[b][0] + rb * 128);
    }
  };

  float lsum[4] = {0.f, 0.f, 0.f, 0.f};
  f32x4 acc[4] = {};

  stage(0, 0);
  asm volatile("s_waitcnt vmcnt(0)" ::: "memory");
  __syncthreads();
  float cfar = biasl[256];
  int swz = (l15 & 7);

  for (int j = 0; j <= qc; ++j) {
    int cur = j & 1;
    if (j < qc) stage(j + 1, cur ^ 1);

    const char* Kc = (const char*)&Kl[cur][0];
    const char* Vc = (const char*)&Vl[cur][0];

    // QK^T : 16q x 64k per wave
    f32x4 sa[4] = {};
#pragma unroll
    for (int ks = 0; ks < 2; ++ks) {
      bf16x8 qa = ks ? qf1 : qf0;
      int slot = lg + 4 * ks;
#pragma unroll
      for (int kt = 0; kt < 4; ++kt) {
        bf16x8 bb = *(const bf16x8*)(Kc + (kt * 16 + l15) * 128 + ((slot ^ swz) * 16));
        sa[kt] = mfma16(qa, bb, sa[kt]);
      }
    }

    // p = exp(s/8 + bias - 6); far tiles (j <= qc-3) have constant bias
    float p[4][4];
    if (j >= qc - 2) {
      int kgb = j * 64 + l15;
      int qgb = qc * 64 + wave * 16 + lg * 4;
#pragma unroll
      for (int kt = 0; kt < 4; ++kt)
#pragma unroll
        for (int r = 0; r < 4; ++r) {
          int rel = (qgb + r) - (kgb + kt * 16);
          rel = min(max(rel, -128), 128) + 128;
          p[kt][r] = exp2f(fmaf(sa[kt][r], C1L, biasl[rel]));
        }
    } else {
#pragma unroll
      for (int kt = 0; kt < 4; ++kt)
#pragma unroll
        for (int r = 0; r < 4; ++r)
          p[kt][r] = exp2f(fmaf(sa[kt][r], C1L, cfar));
    }
#pragma unroll
    for (int r = 0; r < 4; ++r)
      lsum[r] += (p[0][r] + p[1][r]) + (p[2][r] + p[3][r]);

    // P -> LDS (wave-private rows)
#pragma unroll
    for (int kt = 0; kt < 4; ++kt)
#pragma unroll
      for (int r = 0; r < 4; ++r) {
        __bf16 pb = (__bf16)p[kt][r];
        Pl[(wave * 16 + lg * 4 + r) * 72 + kt * 16 + l15] = *(unsigned short*)&pb;
      }

    // PV
#pragma unroll
    for (int ks = 0; ks < 2; ++ks) {
      bf16x8 pa = *(const bf16x8*)((const char*)Pl +
                    (wave * 16 + l15) * 144 + lg * 16 + ks * 64);
      int slot = lg + 4 * ks;
#pragma unroll
      for (int dt = 0; dt < 4; ++dt) {
        bf16x8 vb = *(const bf16x8*)(Vc + (dt * 16 + l15) * 128 + ((slot ^ swz) * 16));
        acc[dt] = mfma16(pa, vb, acc[dt]);
      }
    }

    asm volatile("s_waitcnt vmcnt(0)" ::: "memory");
    __syncthreads();
  }

  // deferred row-sum: reduce partials over the 16 lanes sharing lg
#pragma unroll
  for (int r = 0; r < 4; ++r) {
    float s = lsum[r];
#pragma unroll
    for (int off = 1; off < 16; off <<= 1) s += __shfl_xor(s, off);
    lsum[r] = s;
  }

  // epilogue: normalize, write bf16 [4096][1024]
#pragma unroll
  for (int r = 0; r < 4; ++r) {
    float inv = 1.0f / lsum[r];
    int s = qc * 64 + wave * 16 + lg * 4 + r;
    size_t row = (size_t)bidx * SEQ + s;
#pragma unroll
    for (int dt = 0; dt < 4; ++dt) {
      float v = acc[dt][r] * inv;
      int col = h * 64 + dt * 16 + l15;
      AOh[row * DM + col] = f2bf(v);
    }
  }
}

// ---------------- k4: output GEMM, plain bf16, f32 out --------------------
// Same structure/swizzle as k_gemm_qkv (128x128x64, 16 K-steps).
__global__ __launch_bounds__(256) void k_gemm_out(
    const unsigned short* __restrict__ Ab, const unsigned short* __restrict__ Bt,
    const float* __restrict__ bo, float* __restrict__ out) {
  __shared__ __align__(16) unsigned short Al[128 * 64];
  __shared__ __align__(16) unsigned short Bl[128 * 64];

  int m0 = blockIdx.x * 128, n0 = blockIdx.y * 128;
  int tid = threadIdx.x, lane = tid & 63, wave = tid >> 6;
  int wr = wave >> 1, wc = wave & 1;
  int l15 = lane & 15, lg = lane >> 4;
  int r3 = lane >> 3, s3 = lane & 7;
  int gsw = (s3 ^ r3) << 4;
  int swz = l15 & 7;

  f32x4 acc[4][4] = {};

  for (int kb = 0; kb < 16; ++kb) {
#pragma unroll
    for (int c = 0; c < 4; ++c) {
      int rb = c * 32 + wave * 8;
      gload_lds16((const char*)Ab + (size_t)(m0 + rb + r3) * 2048 + kb * 128 + gsw,
                  (char*)Al + rb * 128);
      gload_lds16((const char*)Bt + (size_t)(n0 + rb + r3) * 2048 + kb * 128 + gsw,
                  (char*)Bl + rb * 128);
    }
    __syncthreads();
#pragma unroll
    for (int ks = 0; ks < 2; ++ks) {
      int slot = lg + 4 * ks;
      int sofs = ((slot ^ swz) << 4);
      bf16x8 a[4], b[4];
#pragma unroll
      for (int mt = 0; mt < 4; ++mt)
        a[mt] = *(const bf16x8*)((const char*)Al + (wr * 64 + mt * 16 + l15) * 128 + sofs);
#pragma unroll
      for (int nt = 0; nt < 4; ++nt)
        b[nt] = *(const bf16x8*)((const char*)Bl + (wc * 64 + nt * 16 + l15) * 128 + sofs);
#pragma unroll
      for (int mt = 0; mt < 4; ++mt)
#pragma unroll
        for (int nt = 0; nt < 4; ++nt)
          acc[mt][nt] = mfma16(a[mt], b[nt], acc[mt][nt]);
    }
    __syncthreads();
  }

#pragma unroll
  for (int nt = 0; nt < 4; ++nt) {
    int n = n0 + wc * 64 + nt * 16 + l15;
    float bb = bo[n];
#pragma unroll
    for (int mt = 0; mt < 4; ++mt) {
      int mbase = m0 + wr * 64 + mt * 16 + lg * 4;
#pragma unroll
      for (int r = 0; r < 4; ++r)
        out[(size_t)(mbase + r) * DM + n] = acc[mt][nt][r] + bb;
    }
  }
}

// ---------------- launch ---------------------------------------------------
extern "C" void kernel_launch(void* const* d_in, const int* in_sizes, int n_in,
                              void* d_out, int out_size, void* d_ws, size_t ws_size,
                              hipStream_t stream) {
  const float* x  = (const float*)d_in[0];
  const float* Wq = (const float*)d_in[1];
  const float* bq = (const float*)d_in[2];
  const float* Wk = (const float*)d_in[3];
  const float* bk = (const float*)d_in[4];
  const float* Wv = (const float*)d_in[5];
  const float* bv = (const float*)d_in[6];
  const float* Wo = (const float*)d_in[7];
  const float* bo = (const float*)d_in[8];
  const float* rb = (const float*)d_in[9];
  float* out = (float*)d_out;

  char* ws = (char*)d_ws;
  size_t off = 0;
  auto alloc = [&](size_t bytes) {
    char* p = ws + off; off += (bytes + 255) & ~(size_t)255; return p;
  };
  unsigned short* xb   = (unsigned short*)alloc((size_t)NROW * DM * 2);
  unsigned short* Wqt  = (unsigned short*)alloc((size_t)DM * DM * 2);
  unsigned short* Wkt  = (unsigned short*)alloc((size_t)DM * DM * 2);
  unsigned short* Wvt  = (unsigned short*)alloc((size_t)DM * DM * 2);
  unsigned short* Wot  = (unsigned short*)alloc((size_t)DM * DM * 2);
  unsigned short* Qb   = (unsigned short*)alloc((size_t)NROW * DM * 2);
  unsigned short* Kb   = (unsigned short*)alloc((size_t)NROW * DM * 2);
  unsigned short* Vtb  = (unsigned short*)alloc((size_t)NROW * DM * 2);
  unsigned short* AOh  = (unsigned short*)alloc((size_t)NROW * DM * 2);

  k_cvt_x<<<dim3(NROW * DM / 4 / 256), dim3(256), 0, stream>>>(x, xb);
  k_cvt_w<<<dim3(32, 32, 4), dim3(256), 0, stream>>>(Wq, Wk, Wv, Wo,
                                                     Wqt, Wkt, Wvt, Wot);
  k_gemm_qkv<<<dim3(32, 8, 3), dim3(256), 0, stream>>>(xb, Wqt, Wkt, Wvt,
                                                       bq, bk, bv, Qb, Kb, Vtb);
  k_attn<<<dim3(1024), dim3(256), 0, stream>>>(Qb, Kb, Vtb, rb, AOh);
  k_gemm_out<<<dim3(32, 8), dim3(256), 0, stream>>>(AOh, Wot, bo, out);
}